// Round 3
// baseline (456.964 us; speedup 1.0000x reference)
//
#include <hip/hip_runtime.h>
#include <stdint.h>

#define N_SITES 1024
#define BS 2048
#define BLOCK 512
#define SPT 4            // 512 threads * 4 samples = 2048 = BS
#define TAB_STRIDE 20    // 16 floats + 4 pad -> start group (5*sel)%8 uniform
#define QUAD_STRIDE 20

// row-major 4x4: C = A*B
__device__ __forceinline__ void mm4(const float* A, const float* B, float* C) {
#pragma unroll
  for (int a = 0; a < 4; ++a)
#pragma unroll
    for (int k = 0; k < 4; ++k)
      C[a * 4 + k] = fmaf(A[a * 4 + 0], B[0 + k],
                     fmaf(A[a * 4 + 1], B[4 + k],
                     fmaf(A[a * 4 + 2], B[8 + k],
                          A[a * 4 + 3] * B[12 + k])));
}

// Coalesced ballot-based bit pack. bitsT[w*BS + b] bit (j&31) of word j>>5.
// sel bit = 1 if spin==0 (phys 1).
__global__ void pack_bits_kernel(const float* __restrict__ data,
                                 uint32_t* __restrict__ bitsT) {
  const int wave = (int)((blockIdx.x * blockDim.x + threadIdx.x) >> 6);  // 0..32767
  const int lane = (int)(threadIdx.x & 63);
  const int b = wave & 2047;
  const int wp = wave >> 11;  // word pair 0..15
  const int j = (wp * 2 + (lane >> 5)) * 32 + (lane & 31);
  const float spin = data[((size_t)b * N_SITES + j) * 2];
  const unsigned long long m = __ballot(spin < 0.5f);
  if (lane == 0)  bitsT[(size_t)(wp * 2 + 0) * BS + b] = (uint32_t)m;
  if (lane == 32) bitsT[(size_t)(wp * 2 + 1) * BS + b] = (uint32_t)(m >> 32);
}

__global__ void zero_out_kernel(float* __restrict__ out) {
  int i = blockIdx.x * blockDim.x + threadIdx.x;
  if (i < BS) out[i] = 0.0f;
}

// One block per row n. Columns processed 16 at a time = 2 segments of 8.
// Per segment: 256-entry product table built in-LDS via quad tree.
__global__ __launch_bounds__(BLOCK, 6) void amps_fused_kernel(
    const float* __restrict__ tensors, const uint32_t* __restrict__ bitsT,
    float* __restrict__ out) {
  __shared__ __align__(16) float colsL[16 * 32];                  // 2 KB raw cols
  __shared__ __align__(16) float quadL[2 * 2 * 16 * QUAD_STRIDE]; // 5 KB
  __shared__ __align__(16) float tabL[2 * 256 * TAB_STRIDE];      // 40 KB
  __shared__ __align__(16) float tailL[15 * 32];                  // tail cols

  const int n = (N_SITES - 1) - (int)blockIdx.x;  // longest rows first
  const int tid = (int)threadIdx.x;
  const int T16 = n >> 4, r = n & 15;
  const size_t rowbase = (size_t)n * (N_SITES * 32);

  float L[SPT][4];
#pragma unroll
  for (int s = 0; s < SPT; ++s) {
    L[s][0] = 1.f; L[s][1] = 0.f; L[s][2] = 0.f; L[s][3] = 0.f;
  }

  // stage tail columns transposed: tailL[c*32 + sel*16 + a*4 + k]
  if (tid < r * 32) {
    const int c = tid >> 5, e = tid & 31;
    const int a = e >> 3, k = (e >> 1) & 3, i = e & 1;
    tailL[c * 32 + i * 16 + a * 4 + k] =
        tensors[rowbase + (size_t)(16 * T16 + c) * 32 + a * 8 + k * 2 + i];
  }
  __syncthreads();

  uint32_t wd[SPT];
  for (int ci = 0; ci < T16; ++ci) {
    __syncthreads();  // previous chunk's tabL fully consumed
    // stage 16 raw columns: 128 float4s
    if (tid < 128) {
      const float4* g4 = (const float4*)(tensors + rowbase + (size_t)ci * (16 * 32));
      ((float4*)colsL)[tid] = g4[tid];
    }
    __syncthreads();
    // quad products: thread (seg, quad, s4) -> M0(b0)M1(b1)M2(b2)M3(b3)
    if (tid < 64) {
      const int seg = tid >> 5, quad = (tid >> 4) & 1, s4 = tid & 15;
      const float* cb = colsL + (seg * 8 + quad * 4) * 32;
      float M0[16], M1[16], P01[16];
      {
        const int b0 = s4 & 1, b1 = (s4 >> 1) & 1;
#pragma unroll
        for (int x = 0; x < 4; ++x)
#pragma unroll
          for (int y = 0; y < 4; ++y) {
            M0[x * 4 + y] = cb[0 * 32 + x * 8 + y * 2 + b0];
            M1[x * 4 + y] = cb[1 * 32 + x * 8 + y * 2 + b1];
          }
        mm4(M0, M1, P01);
      }
      float M2[16], M3[16], P23[16], P[16];
      {
        const int b2 = (s4 >> 2) & 1, b3 = (s4 >> 3) & 1;
#pragma unroll
        for (int x = 0; x < 4; ++x)
#pragma unroll
          for (int y = 0; y < 4; ++y) {
            M2[x * 4 + y] = cb[2 * 32 + x * 8 + y * 2 + b2];
            M3[x * 4 + y] = cb[3 * 32 + x * 8 + y * 2 + b3];
          }
        mm4(M2, M3, P23);
      }
      mm4(P01, P23, P);
      float* dst = quadL + ((seg * 2 + quad) * 16 + s4) * QUAD_STRIDE;
#pragma unroll
      for (int i = 0; i < 16; ++i) dst[i] = P[i];
    }
    __syncthreads();
    // finals: all 512 threads, one 8-col product each: QA(lo nibble)*QB(hi)
    {
      const int seg = tid >> 8, sel = tid & 255;
      const float4* qa = (const float4*)(quadL + ((seg * 2 + 0) * 16 + (sel & 15)) * QUAD_STRIDE);
      const float4* qb = (const float4*)(quadL + ((seg * 2 + 1) * 16 + (sel >> 4)) * QUAD_STRIDE);
      float A[16], B[16], C[16];
#pragma unroll
      for (int q = 0; q < 4; ++q) {
        float4 va = qa[q], vb = qb[q];
        A[4 * q] = va.x; A[4 * q + 1] = va.y; A[4 * q + 2] = va.z; A[4 * q + 3] = va.w;
        B[4 * q] = vb.x; B[4 * q + 1] = vb.y; B[4 * q + 2] = vb.z; B[4 * q + 3] = vb.w;
      }
      mm4(A, B, C);
      float4* dst = (float4*)(tabL + (seg * 256 + sel) * TAB_STRIDE);
#pragma unroll
      for (int q = 0; q < 4; ++q)
        dst[q] = make_float4(C[4 * q], C[4 * q + 1], C[4 * q + 2], C[4 * q + 3]);
    }
    __syncthreads();
    // main phase: 4 samples/thread, 2 segments
    if ((ci & 1) == 0) {
      const size_t wb = (size_t)(ci >> 1) * BS + tid;
#pragma unroll
      for (int sp = 0; sp < SPT; ++sp) wd[sp] = bitsT[wb + sp * BLOCK];
    }
#pragma unroll
    for (int seg = 0; seg < 2; ++seg) {
      const int shift = ((ci & 1) << 4) + (seg << 3);
      const float* tb = tabL + seg * (256 * TAB_STRIDE);
#pragma unroll
      for (int sp = 0; sp < SPT; ++sp) {
        const int sel = (int)((wd[sp] >> shift) & 255u);
        const float4* mp = (const float4*)(tb + (size_t)sel * TAB_STRIDE);
        float4 m0 = mp[0], m1 = mp[1], m2 = mp[2], m3 = mp[3];
        const float a0 = L[sp][0], a1 = L[sp][1], a2 = L[sp][2], a3 = L[sp][3];
        L[sp][0] = fmaf(a3, m3.x, fmaf(a2, m2.x, fmaf(a1, m1.x, a0 * m0.x)));
        L[sp][1] = fmaf(a3, m3.y, fmaf(a2, m2.y, fmaf(a1, m1.y, a0 * m0.y)));
        L[sp][2] = fmaf(a3, m3.z, fmaf(a2, m2.z, fmaf(a1, m1.z, a0 * m0.z)));
        L[sp][3] = fmaf(a3, m3.w, fmaf(a2, m2.w, fmaf(a1, m1.w, a0 * m0.w)));
      }
    }
  }

  // tail columns j = 16*T16 .. n-1, 1-bit indexed
  for (int c = 0; c < r; ++c) {
    const int j = 16 * T16 + c;
    const uint32_t sh = (uint32_t)(j & 31);
    const size_t wb = (size_t)(j >> 5) * BS + tid;
    const float* tbase = tailL + c * 32;
#pragma unroll
    for (int sp = 0; sp < SPT; ++sp) {
      const uint32_t bit = (bitsT[wb + sp * BLOCK] >> sh) & 1u;
      const float4* mp = (const float4*)(tbase + bit * 16);
      float4 m0 = mp[0], m1 = mp[1], m2 = mp[2], m3 = mp[3];
      const float a0 = L[sp][0], a1 = L[sp][1], a2 = L[sp][2], a3 = L[sp][3];
      L[sp][0] = fmaf(a3, m3.x, fmaf(a2, m2.x, fmaf(a1, m1.x, a0 * m0.x)));
      L[sp][1] = fmaf(a3, m3.y, fmaf(a2, m2.y, fmaf(a1, m1.y, a0 * m0.y)));
      L[sp][2] = fmaf(a3, m3.z, fmaf(a2, m2.z, fmaf(a1, m1.z, a0 * m0.z)));
      L[sp][3] = fmaf(a3, m3.w, fmaf(a2, m2.w, fmaf(a1, m1.w, a0 * m0.w)));
    }
  }

  // epilogue: 2-way log-softmax vs diagonal tensor, pick observed phys
  const float* dgp = tensors + rowbase + (size_t)n * 32;
  float dg0[4], dg1[4];
#pragma unroll
  for (int a = 0; a < 4; ++a) {
    dg0[a] = dgp[a * 8 + 0];
    dg1[a] = dgp[a * 8 + 1];
  }
  const size_t wb = (size_t)(n >> 5) * BS + tid;
  const uint32_t shn = (uint32_t)(n & 31);
#pragma unroll
  for (int sp = 0; sp < SPT; ++sp) {
    const int b = tid + sp * BLOCK;
    const uint32_t sel = (bitsT[wb + sp * BLOCK] >> shn) & 1u;
    float l0 = 0.f, l1 = 0.f;
#pragma unroll
    for (int a = 0; a < 4; ++a) {
      l0 = fmaf(L[sp][a], dg0[a], l0);
      l1 = fmaf(L[sp][a], dg1[a], l1);
    }
    const float mx = fmaxf(l0, l1);
    const float lse = mx + logf(expf(l0 - mx) + expf(l1 - mx));
    atomicAdd(&out[b], (sel ? l1 : l0) - lse);
  }
}

extern "C" void kernel_launch(void* const* d_in, const int* in_sizes, int n_in,
                              void* d_out, int out_size, void* d_ws, size_t ws_size,
                              hipStream_t stream) {
  const float* data = (const float*)d_in[0];     // (BS, N, 2) fp32
  const float* tensors = (const float*)d_in[1];  // (N, N, 4, 4, 2) fp32
  float* out = (float*)d_out;                    // (BS,) fp32
  uint32_t* bitsT = (uint32_t*)d_ws;             // 32*2048*4 = 256 KB

  pack_bits_kernel<<<(BS * 32 / 2) * 64 / 256, 256, 0, stream>>>(data, bitsT);
  zero_out_kernel<<<(BS + 255) / 256, 256, 0, stream>>>(out);
  amps_fused_kernel<<<N_SITES, BLOCK, 0, stream>>>(tensors, bitsT, out);
}